// Round 1
// baseline (639.580 us; speedup 1.0000x reference)
//
#include <hip/hip_runtime.h>
#include <math.h>

#define Tn   400
#define Bn   2
#define Sn   96000
#define NHh  128
#define NNn  513
#define NFFT 1024
#define HOPs 256
#define PADs 512
#define TS   376      // 1 + Sn/HOPs
#define LPn  97024    // NFFT + (TS-1)*HOPs
#define CUT  21600.0f // SR*0.45
#define DPI  3.14159265358979323846

__device__ __forceinline__ float sigmoidf_(float x){ return 1.0f/(1.0f+expf(-x)); }
__device__ __forceinline__ float softplusf_(float x){ return fmaxf(x,0.0f)+log1pf(expf(-fabsf(x))); }

// ---------------- setup: per-batch scalars + f64 prefix table -------------
__global__ void k_setup(const float* f0, float* fs, double* P) {
  int b = threadIdx.x;
  if (b < Bn) {
    const float* f = f0 + b*Tn;
    // f0_mean over frames, clipped at 20 (used by noise warp + b_max)
    double sm = 0.0;
    for (int t=0;t<Tn;t++) sm += fmax((double)f[t], 20.0);
    float f0m = (float)(sm / (double)Tn);
    fs[b] = f0m;
    float midi = 69.0f + 12.0f * log2f(f0m/440.0f);
    fs[2+b] = 0.0008f * expf(-(midi-21.0f)*(1.0f/88.0f) * 2.302585093f); // b_max
    // P[m] = sum_{m'<m} (f0[m'] + f0[m'+1]),  m = 0..399
    double* Pb = P + b*Tn;
    double acc = 0.0;
    for (int m=0;m<Tn;m++){ Pb[m] = acc; if (m < Tn-1) acc += (double)f[m] + (double)f[m+1]; }
    // mean of upsampled f0 (exact closed form), for n_active
    double Ctot = 120.0*((double)f[0] + Pb[Tn-1] + (double)f[Tn-1]);
    double fupmean = Ctot / (double)Sn;
    int cnt = 0;
    for (int k=1;k<=NHh;k++) if ((float)k * (float)fupmean < CUT) cnt++;
    if (cnt < 1) cnt = 1;
    fs[4+b] = (float)cnt;
  }
}

// -------- frame-rate: encode + pre MLP + gi = x@W_ih^T + b_ih -------------
__global__ void __launch_bounds__(128) k_frame1(
    const float* f0, const int* vel,
    const float* Wp1, const float* bp1,
    const float* Wp2, const float* bp2,
    const float* Wih, const float* bih,
    float* gi) {
  int bt = blockIdx.x; int b = bt / Tn, t = bt % Tn;
  __shared__ float x[72];
  __shared__ float y1[128];
  __shared__ float y2[128];
  int tid = threadIdx.x;
  if (tid < 72) {
    if (tid < 64) {
      float fv = f0[b*Tn+t];
      float fsv = fmaxf(fv, 20.0f);
      float fn = (logf(fsv) - 2.99573227355399f) * (1.0f/5.52146091786225f);
      fn = fminf(fmaxf(fn,0.0f),1.0f);
      int j = (tid>>1) + 1;
      float ang = (float)DPI * (float)j * fn;
      x[tid] = (tid & 1) ? cosf(ang) : sinf(ang);   // (f0>0) always true here
    } else {
      int i = tid - 64;
      float vn = fminf(fmaxf((float)vel[b]*(1.0f/7.0f),0.0f),1.0f);
      int j = (i>>1)+1;
      float ang = (float)DPI * (float)j * vn;
      x[tid] = (i & 1) ? cosf(ang) : sinf(ang);
    }
  }
  __syncthreads();
  {
    float a = bp1[tid];
    #pragma unroll 8
    for (int i=0;i<72;i++) a += x[i]*Wp1[i*128+tid];
    y1[tid] = fmaxf(a,0.0f);
  }
  __syncthreads();
  {
    float a = bp2[tid];
    #pragma unroll 8
    for (int i=0;i<128;i++) a += y1[i]*Wp2[i*128+tid];
    y2[tid] = fmaxf(a,0.0f);
  }
  __syncthreads();
  float* gout = gi + ((size_t)b*Tn + t)*192;
  for (int g = tid; g < 192; g += 128) {
    float s = bih[g];
    const float* wr = Wih + g*128;
    #pragma unroll 8
    for (int d=0; d<128; d++) s += y2[d]*wr[d];
    gout[g] = s;
  }
}

// ---------------- GRU: sequential over T, one block per batch ------------
__global__ void __launch_bounds__(192) k_gru(const float* gi, const float* Whh,
                                             const float* bhh, float* hsout) {
  int b = blockIdx.x;
  int j = threadIdx.x; // 0..191
  __shared__ float h[64];
  __shared__ float gh[192];
  float w[64];
  #pragma unroll
  for (int i=0;i<64;i++) w[i] = Whh[j*64+i];
  float bj = bhh[j];
  if (j < 64) h[j] = 0.0f;
  __syncthreads();
  const float* gib = gi + (size_t)b*Tn*192;
  float* hb = hsout + (size_t)b*Tn*64;
  for (int t=0;t<Tn;t++) {
    float s0=0.f,s1=0.f,s2=0.f,s3=0.f;
    #pragma unroll
    for (int i=0;i<64;i+=4) {
      s0 += h[i+0]*w[i+0]; s1 += h[i+1]*w[i+1];
      s2 += h[i+2]*w[i+2]; s3 += h[i+3]*w[i+3];
    }
    gh[j] = bj + ((s0+s1)+(s2+s3));
    __syncthreads();
    if (j < 64) {
      const float* g = gib + t*192;
      float r = sigmoidf_(g[j]      + gh[j]);
      float z = sigmoidf_(g[64+j]   + gh[64+j]);
      float n = tanhf(g[128+j] + r*gh[128+j]);
      float hn = (1.0f - z)*n + z*h[j];
      h[j] = hn;
      hb[t*64+j] = hn;
    }
    __syncthreads();
  }
}

// ------------- post-MLP + all heads, one block per (b,t) -----------------
__global__ void __launch_bounds__(256) k_heads(
    const float* hs, const float* Wpost, const float* bpost,
    const float* Wharm, const float* bharm,
    const float* Wamp, const float* bamp,
    const float* Wnoise, const float* bnoise,
    const float* Wnamp, const float* bnamp,
    const float* WB, const float* bB,
    float* harm, float* nmag, float* fs) {
  int bt = blockIdx.x; int b = bt / Tn, t = bt % Tn;
  __shared__ float h64[64];
  __shared__ float fp[128];
  __shared__ float lg[256];
  __shared__ float red[8]; // mx0,mx1,sum0,sum1,amp0,amp1,namp0,namp1
  int tid = threadIdx.x;
  if (tid < 64) h64[tid] = hs[((size_t)b*Tn+t)*64+tid];
  __syncthreads();
  if (tid < 128) {
    float a = bpost[tid];
    #pragma unroll 8
    for (int i=0;i<64;i++) a += h64[i]*Wpost[i*128+tid];
    fp[tid] = fmaxf(a,0.0f);
  }
  __syncthreads();
  { // harmonic logits: tid -> (c = tid>>7, n = tid&127)
    int c = tid >> 7, n = tid & 127;
    float a = bharm[c*128+n];
    const float* w = Wharm + (size_t)c*128*128 + n;
    #pragma unroll 8
    for (int d=0;d<128;d++) a += fp[d]*w[d*128];
    lg[tid] = a;
  }
  __syncthreads();
  if (tid < 2) {
    const float* l = lg + tid*128;
    float mx = l[0];
    for (int n=1;n<128;n++) mx = fmaxf(mx,l[n]);
    float sm = 0.f; for (int n=0;n<128;n++) sm += expf(l[n]-mx);
    red[tid] = mx; red[2+tid] = sm;
    float aa = bamp[tid];
    for (int d=0;d<128;d++) aa += fp[d]*Wamp[tid*128+d];
    red[4+tid] = softplusf_(aa);
    float na = bnamp[tid];
    for (int d=0;d<128;d++) na += fp[d]*Wnamp[tid*128+d];
    red[6+tid] = softplusf_(na);
  } else if (tid == 2) {
    float bb = bB[0];
    for (int d=0;d<128;d++) bb += fp[d]*WB[d];
    atomicAdd(&fs[6+b], sigmoidf_(bb));
  }
  __syncthreads();
  { // harm_amps = softmax * amp
    int c = tid >> 7, n = tid & 127;
    float v = expf(lg[tid]-red[c]) / red[2+c] * red[4+c];
    harm[(((size_t)c*Bn + b)*Tn + t)*128 + n] = v;
  }
  // noise magnitudes: 2*513 outputs
  for (int o = tid; o < 2*NNn; o += 256) {
    int c = (o < NNn) ? 0 : 1; int n = o - c*NNn;
    float a = bnoise[c*NNn+n];
    const float* w = Wnoise + (size_t)c*128*NNn + n;
    #pragma unroll 8
    for (int d=0;d<128;d++) a += fp[d]*w[(size_t)d*NNn];
    nmag[(((size_t)c*Bn + b)*Tn + t)*NNn + n] = sigmoidf_(a) * red[6+c];
  }
}

// --------- inh + per-(b,k) frequency ratios r = k*sqrt(1+inh k^2) --------
__global__ void k_inh(float* fs, double* rk) {
  int tid = threadIdx.x; // 256
  __shared__ double inh_s[2];
  if (tid < 2) {
    float inh = fs[6+tid]*(1.0f/(float)Tn) * fs[2+tid];
    fs[8+tid] = inh;
    inh_s[tid] = (double)inh;
  }
  __syncthreads();
  int b = tid >> 7, k = (tid & 127) + 1;
  double kk = (double)k;
  rk[b*128 + (k-1)] = kk * sqrt(1.0 + inh_s[b]*kk*kk);
}

// ---------------- harmonic synthesis: thread per (b,s) -------------------
__global__ void __launch_bounds__(256) k_harm(
    const float* f0, const float* harm, const double* P,
    const double* rk, const float* fs, float* sigh) {
  int b = blockIdx.y;
  int s = blockIdx.x*256 + threadIdx.x; // < 96000 exactly
  __shared__ double rks[128];
  __shared__ float  rkf[128];
  if (threadIdx.x < 128) {
    double r = rk[b*128+threadIdx.x];
    rks[threadIdx.x] = r; rkf[threadIdx.x] = (float)r;
  }
  __syncthreads();
  const float* f = f0 + b*Tn;
  float posf = ((float)s + 0.5f) * (400.0f/96000.0f) - 0.5f;
  posf = fminf(fmaxf(posf, 0.0f), 399.0f);
  int lo = (int)floorf(posf);
  int hi = min(lo+1, 399);
  float fr = posf - (float)lo;
  float f0up = f[lo]*(1.0f-fr) + f[hi]*fr;
  // closed-form inclusive prefix sum of f0_up (f64)
  double C;
  if (s < 120) {
    C = (double)(s+1) * (double)f[0];
  } else if (s < 95880) {
    int m = (s-120)/240;
    int j = s - 120 - 240*m;
    double fm = (double)f[m], fm1 = (double)f[m+1];
    double jp = (double)(j+1);
    C = 120.0*((double)f[0] + P[b*Tn+m]) + jp*fm + (fm1-fm)*jp*jp*(1.0/480.0);
  } else {
    C = 120.0*((double)f[0] + P[b*Tn+399]) + (double)(s-95880+1)*(double)f[399];
  }
  double Phi = C * (2.0*DPI/48000.0);
  const float* hLlo = harm + (((size_t)0*Bn + b)*Tn + lo)*128;
  const float* hLhi = harm + (((size_t)0*Bn + b)*Tn + hi)*128;
  const float* hRlo = harm + (((size_t)1*Bn + b)*Tn + lo)*128;
  const float* hRhi = harm + (((size_t)1*Bn + b)*Tn + hi)*128;
  float accL=0.f, accR=0.f;
  for (int k=0;k<128;k++) {
    float finst = f0up * rkf[k];
    if (finst < CUT) {
      double u = rks[k]*Phi * (1.0/(2.0*DPI));
      u -= floor(u);
      float sv = __sinf((float)u * 6.28318530717959f);
      float aL = hLlo[k]*(1.0f-fr) + hLhi[k]*fr;
      float aR = hRlo[k]*(1.0f-fr) + hRhi[k]*fr;
      accL += aL*sv; accR += aR*sv;
    }
  }
  float na = fs[4+b];
  sigh[((size_t)b*2+0)*Sn + s] = accL/na;
  sigh[((size_t)b*2+1)*Sn + s] = accR/na;
}

// ------ noise: frame -> window -> FFT -> shape -> iFFT -> window -> OLA ---
__global__ void __launch_bounds__(256) k_noise(
    const float* noiseL, const float* noiseR,
    const float* nmag, const float* fs, float* ola) {
  int t = blockIdx.x;       // 0..375
  int sig = blockIdx.y;     // b*2 + c
  int b = sig >> 1, c = sig & 1;
  const float* noise = (c==0 ? noiseL : noiseR) + (size_t)b*Sn;
  __shared__ float re[1024], im[1024];
  __shared__ float twc[512], tws[512];
  __shared__ float wdw[1024];
  int tid = threadIdx.x;
  for (int j=tid; j<512; j+=256) {
    float ang = (float)(2.0*DPI) * (float)j * (1.0f/1024.0f);
    twc[j] = cosf(ang); tws[j] = sinf(ang);
  }
  for (int i=tid; i<1024; i+=256)
    wdw[i] = 0.5f - 0.5f*cosf((float)(2.0*DPI)*(float)i*(1.0f/1024.0f));
  __syncthreads();
  // load frame (reflect pad), window, store bit-reversed
  for (int i=tid;i<1024;i+=256) {
    int q = t*HOPs + i - PADs;
    if (q < 0) q = -q;
    if (q >= Sn) q = 2*Sn - 2 - q;
    float v = noise[q]*wdw[i];
    int br = (int)(__brev((unsigned)i) >> 22);
    re[br] = v; im[br] = 0.0f;
  }
  __syncthreads();
  // forward FFT (e^{-i theta})
  for (int st=1; st<=10; st++) {
    int half = 1<<(st-1);
    #pragma unroll
    for (int w=0;w<2;w++) {
      int bid = tid + w*256;
      int pos = bid & (half-1);
      int i0 = ((bid >> (st-1)) << st) + pos;
      int i1 = i0 + half;
      int j = pos << (10-st);
      float cr = twc[j], ci = -tws[j];
      float xr = re[i1], xi = im[i1];
      float tr = cr*xr - ci*xi, ti = cr*xi + ci*xr;
      float ar = re[i0], ai = im[i0];
      re[i1] = ar - tr; im[i1] = ai - ti;
      re[i0] = ar + tr; im[i0] = ai + ti;
    }
    __syncthreads();
  }
  // shape bins 0..512 with freq-warped, time-interped noise mags
  float f0m = fs[b];
  float pp = ((float)t + 0.5f) * (400.0f/376.0f) - 0.5f;
  pp = fminf(fmaxf(pp,0.0f),399.0f);
  int tlo = (int)floorf(pp); int thi = min(tlo+1, 399); float tfr = pp - (float)tlo;
  const float* nm = nmag + (((size_t)c*Bn + b)*Tn)*NNn;
  for (int k=tid;k<=512;k+=256) {
    float src = (float)k * 46.875f / f0m * (513.0f/128.0f);
    src = fminf(fmaxf(src,0.0f),512.0f);
    int flo = (int)src; int fhi = min(flo+1,512); float ffr = src - (float)flo;
    float vlo = nm[(size_t)tlo*NNn+flo]*(1.0f-tfr) + nm[(size_t)thi*NNn+flo]*tfr;
    float vhi = nm[(size_t)tlo*NNn+fhi]*(1.0f-tfr) + nm[(size_t)thi*NNn+fhi]*tfr;
    float mag = vlo + ffr*(vhi-vlo);
    re[k] *= mag; im[k] *= mag;
  }
  __syncthreads();
  // Hermitian mirror for bins 513..1023
  for (int k=tid+513; k<1024; k+=256) {
    re[k] = re[1024-k]; im[k] = -im[1024-k];
  }
  __syncthreads();
  // bit-reverse permute (involution; pair owned by smaller index)
  for (int i=tid;i<1024;i+=256) {
    int j = (int)(__brev((unsigned)i)>>22);
    if (i < j) {
      float a=re[i]; re[i]=re[j]; re[j]=a;
      float bb=im[i]; im[i]=im[j]; im[j]=bb;
    }
  }
  __syncthreads();
  // inverse FFT (e^{+i theta})
  for (int st=1; st<=10; st++) {
    int half = 1<<(st-1);
    #pragma unroll
    for (int w=0;w<2;w++) {
      int bid = tid + w*256;
      int pos = bid & (half-1);
      int i0 = ((bid >> (st-1)) << st) + pos;
      int i1 = i0 + half;
      int j = pos << (10-st);
      float cr = twc[j], ci = tws[j];
      float xr = re[i1], xi = im[i1];
      float tr = cr*xr - ci*xi, ti = cr*xi + ci*xr;
      float ar = re[i0], ai = im[i0];
      re[i1] = ar - tr; im[i1] = ai - ti;
      re[i0] = ar + tr; im[i0] = ai + ti;
    }
    __syncthreads();
  }
  float* olab = ola + (size_t)sig*LPn;
  for (int i=tid;i<1024;i+=256) {
    float y = re[i] * (1.0f/1024.0f) * wdw[i];
    atomicAdd(&olab[t*HOPs + i], y);
  }
}

// ------------- final: (harm + ola/wsq) * loudness ------------------------
__global__ void __launch_bounds__(256) k_final(
    const float* loud, const float* sigh, const float* ola, float* out) {
  int b = blockIdx.y;
  int s = blockIdx.x*256 + threadIdx.x;
  float posf = ((float)s + 0.5f)*(400.0f/96000.0f) - 0.5f;
  posf = fminf(fmaxf(posf,0.0f),399.0f);
  int lo=(int)floorf(posf); int hi=min(lo+1,399); float fr=posf-(float)lo;
  const float* ld = loud + b*Tn;
  float lv = exp10f(ld[lo]*0.05f)*(1.0f-fr) + exp10f(ld[hi]*0.05f)*fr;
  int p = PADs + s;
  int t0 = (p >= 1023) ? ((p - 1023 + 255) >> 8) : 0;
  int t1 = min(TS-1, p >> 8);
  float wsq = 0.0f;
  for (int t=t0;t<=t1;t++) {
    int i = p - (t<<8);
    float w = 0.5f - 0.5f*cosf((float)(2.0*DPI)*(float)i*(1.0f/1024.0f));
    wsq += w*w;
  }
  float denom = (wsq > 1e-11f) ? wsq : 1.0f;
  for (int c=0;c<2;c++) {
    float hv = sigh[((size_t)b*2+c)*Sn+s];
    float nv = ola[(size_t)(b*2+c)*LPn + p] / denom;
    out[((size_t)b*2+c)*Sn + s] = (hv + nv)*lv;
  }
}

extern "C" void kernel_launch(void* const* d_in, const int* in_sizes, int n_in,
                              void* d_out, int out_size, void* d_ws, size_t ws_size,
                              hipStream_t stream) {
  const float* f0    = (const float*)d_in[0];
  const float* loud  = (const float*)d_in[1];
  const float* nL    = (const float*)d_in[2];
  const float* nR    = (const float*)d_in[3];
  const float* Wp1   = (const float*)d_in[4];  const float* bp1 = (const float*)d_in[5];
  const float* Wp2   = (const float*)d_in[6];  const float* bp2 = (const float*)d_in[7];
  const float* Wih   = (const float*)d_in[8];  const float* Whh = (const float*)d_in[9];
  const float* bih   = (const float*)d_in[10]; const float* bhh = (const float*)d_in[11];
  const float* Wpost = (const float*)d_in[12]; const float* bpost=(const float*)d_in[13];
  const float* Wharm = (const float*)d_in[14]; const float* bharm=(const float*)d_in[15];
  const float* Wamp  = (const float*)d_in[16]; const float* bamp =(const float*)d_in[17];
  const float* Wnoise= (const float*)d_in[18]; const float* bnoise=(const float*)d_in[19];
  const float* Wnamp = (const float*)d_in[20]; const float* bnamp=(const float*)d_in[21];
  const float* WB    = (const float*)d_in[22]; const float* bB  = (const float*)d_in[23];
  const int*   vel   = (const int*)d_in[24];
  float* out = (float*)d_out;

  // workspace carve (doubles first for alignment)
  char* w = (char*)d_ws;
  double* P    = (double*)w; w += (size_t)Bn*Tn*sizeof(double);
  double* rk   = (double*)w; w += (size_t)Bn*128*sizeof(double);
  float* gi    = (float*)w;  w += (size_t)Bn*Tn*192*sizeof(float);
  float* hsb   = (float*)w;  w += (size_t)Bn*Tn*64*sizeof(float);
  float* harm  = (float*)w;  w += (size_t)2*Bn*Tn*128*sizeof(float);
  float* nmag  = (float*)w;  w += (size_t)2*Bn*Tn*NNn*sizeof(float);
  float* sigh  = (float*)w;  w += (size_t)Bn*2*Sn*sizeof(float);
  float* ola   = (float*)w;  w += (size_t)Bn*2*LPn*sizeof(float);
  float* fscal = (float*)w;  w += 32*sizeof(float);

  hipMemsetAsync(ola, 0, (size_t)Bn*2*LPn*sizeof(float), stream);
  hipMemsetAsync(fscal, 0, 32*sizeof(float), stream);

  k_setup<<<1, 64, 0, stream>>>(f0, fscal, P);
  k_frame1<<<Bn*Tn, 128, 0, stream>>>(f0, vel, Wp1,bp1, Wp2,bp2, Wih,bih, gi);
  k_gru<<<Bn, 192, 0, stream>>>(gi, Whh, bhh, hsb);
  k_heads<<<Bn*Tn, 256, 0, stream>>>(hsb, Wpost,bpost, Wharm,bharm, Wamp,bamp,
                                     Wnoise,bnoise, Wnamp,bnamp, WB,bB,
                                     harm, nmag, fscal);
  k_inh<<<1, 256, 0, stream>>>(fscal, rk);
  dim3 gh(Sn/256, Bn);
  k_harm<<<gh, 256, 0, stream>>>(f0, harm, P, rk, fscal, sigh);
  dim3 gn(TS, Bn*2);
  k_noise<<<gn, 256, 0, stream>>>(nL, nR, nmag, fscal, ola);
  dim3 gf(Sn/256, Bn);
  k_final<<<gf, 256, 0, stream>>>(loud, sigh, ola, out);
}

// Round 2
// 511.126 us; speedup vs baseline: 1.2513x; 1.2513x over previous
//
#include <hip/hip_runtime.h>
#include <math.h>

#define Tn   400
#define Bn   2
#define Sn   96000
#define NHh  128
#define NNn  513
#define NFFT 1024
#define HOPs 256
#define PADs 512
#define TS   376      // 1 + Sn/HOPs
#define LPn  97024    // NFFT + (TS-1)*HOPs
#define CUT  21600.0f // SR*0.45
#define DPI  3.14159265358979323846

__device__ __forceinline__ float sigmoidf_(float x){ return 1.0f/(1.0f+expf(-x)); }
__device__ __forceinline__ float softplusf_(float x){ return fmaxf(x,0.0f)+log1pf(expf(-fabsf(x))); }

// ---------------- setup: per-batch scalars + f64 prefix table -------------
__global__ void k_setup(const float* f0, float* fs, double* P) {
  int b = threadIdx.x;
  if (b < Bn) {
    const float* f = f0 + b*Tn;
    double sm = 0.0;
    for (int t=0;t<Tn;t++) sm += fmax((double)f[t], 20.0);
    float f0m = (float)(sm / (double)Tn);
    fs[b] = f0m;
    float midi = 69.0f + 12.0f * log2f(f0m/440.0f);
    fs[2+b] = 0.0008f * expf(-(midi-21.0f)*(1.0f/88.0f) * 2.302585093f); // b_max
    double* Pb = P + b*Tn;
    double acc = 0.0;
    for (int m=0;m<Tn;m++){ Pb[m] = acc; if (m < Tn-1) acc += (double)f[m] + (double)f[m+1]; }
    double Ctot = 120.0*((double)f[0] + Pb[Tn-1] + (double)f[Tn-1]);
    double fupmean = Ctot / (double)Sn;
    int cnt = 0;
    for (int k=1;k<=NHh;k++) if ((float)k * (float)fupmean < CUT) cnt++;
    if (cnt < 1) cnt = 1;
    fs[4+b] = (float)cnt;
  }
}

// -------- frame-rate: encode + pre MLP + gi = x@W_ih^T + b_ih -------------
__global__ void __launch_bounds__(128) k_frame1(
    const float* f0, const int* vel,
    const float* Wp1, const float* bp1,
    const float* Wp2, const float* bp2,
    const float* Wih, const float* bih,
    float* gi) {
  int bt = blockIdx.x; int b = bt / Tn, t = bt % Tn;
  __shared__ float x[72];
  __shared__ float y1[128];
  __shared__ float y2[128];
  int tid = threadIdx.x;
  if (tid < 72) {
    if (tid < 64) {
      float fv = f0[b*Tn+t];
      float fsv = fmaxf(fv, 20.0f);
      float fn = (logf(fsv) - 2.99573227355399f) * (1.0f/5.52146091786225f);
      fn = fminf(fmaxf(fn,0.0f),1.0f);
      int j = (tid>>1) + 1;
      float ang = (float)DPI * (float)j * fn;
      x[tid] = (tid & 1) ? cosf(ang) : sinf(ang);
    } else {
      int i = tid - 64;
      float vn = fminf(fmaxf((float)vel[b]*(1.0f/7.0f),0.0f),1.0f);
      int j = (i>>1)+1;
      float ang = (float)DPI * (float)j * vn;
      x[tid] = (i & 1) ? cosf(ang) : sinf(ang);
    }
  }
  __syncthreads();
  {
    float a = bp1[tid];
    #pragma unroll 8
    for (int i=0;i<72;i++) a += x[i]*Wp1[i*128+tid];
    y1[tid] = fmaxf(a,0.0f);
  }
  __syncthreads();
  {
    float a = bp2[tid];
    #pragma unroll 8
    for (int i=0;i<128;i++) a += y1[i]*Wp2[i*128+tid];
    y2[tid] = fmaxf(a,0.0f);
  }
  __syncthreads();
  float* gout = gi + ((size_t)b*Tn + t)*192;
  for (int g = tid; g < 192; g += 128) {
    float s = bih[g];
    const float* wr = Wih + g*128;
    #pragma unroll 8
    for (int d=0; d<128; d++) s += y2[d]*wr[d];
    gout[g] = s;
  }
}

// ---------------- GRU: sequential over T, one block per batch ------------
// W_hh row held in 16 named float4 REGISTERS (R0 had it spilled to scratch:
// VGPR_Count=52 < 64 needed -> 400 steps of scratch reads = 375 us).
// gi[t+1] prefetched at top of step t so global latency hides behind matvec.
#define FMA4(acc, wv, hv) \
  acc = fmaf((wv).x,(hv).x, fmaf((wv).y,(hv).y, fmaf((wv).z,(hv).z, fmaf((wv).w,(hv).w, acc))));

__global__ void __launch_bounds__(192) k_gru(const float* gi, const float* Whh,
                                             const float* bhh, float* hsout) {
  int b = blockIdx.x;
  int j = threadIdx.x; // 0..191
  __shared__ float h[64];
  __shared__ float gh[192];
  const float4* W4 = (const float4*)(Whh + (size_t)j*64);
  float4 w0=W4[0], w1=W4[1], w2=W4[2],  w3=W4[3],  w4=W4[4],  w5=W4[5],  w6=W4[6],  w7=W4[7];
  float4 w8=W4[8], w9=W4[9], w10=W4[10],w11=W4[11],w12=W4[12],w13=W4[13],w14=W4[14],w15=W4[15];
  float bj = bhh[j];
  const float* gib = gi + (size_t)b*Tn*192;
  float* hb = hsout + (size_t)b*Tn*64;
  bool lane64 = (j < 64);          // wave 0 handles gates (wave-uniform branch)
  float g0=0.f,g1=0.f,g2=0.f;
  if (lane64) {
    h[j] = 0.0f;
    g0 = gib[j]; g1 = gib[64+j]; g2 = gib[128+j];
  }
  __syncthreads();
  const float4* h4 = (const float4*)h;
  for (int t=0;t<Tn;t++) {
    // prefetch next step's gi BEFORE the matvec (hides global latency)
    float n0=0.f,n1=0.f,n2=0.f;
    if (lane64 && (t < Tn-1)) {
      const float* g = gib + (size_t)(t+1)*192;
      n0 = g[j]; n1 = g[64+j]; n2 = g[128+j];
    }
    // h broadcast from LDS into registers, fully-unrolled FMA dot
    float4 a0=h4[0], a1=h4[1], a2=h4[2],  a3=h4[3],  a4=h4[4],  a5=h4[5],  a6=h4[6],  a7=h4[7];
    float4 a8=h4[8], a9=h4[9], a10=h4[10],a11=h4[11],a12=h4[12],a13=h4[13],a14=h4[14],a15=h4[15];
    float s0=0.f,s1=0.f,s2=0.f,s3=0.f;
    FMA4(s0,w0,a0)   FMA4(s1,w1,a1)   FMA4(s2,w2,a2)   FMA4(s3,w3,a3)
    FMA4(s0,w4,a4)   FMA4(s1,w5,a5)   FMA4(s2,w6,a6)   FMA4(s3,w7,a7)
    FMA4(s0,w8,a8)   FMA4(s1,w9,a9)   FMA4(s2,w10,a10) FMA4(s3,w11,a11)
    FMA4(s0,w12,a12) FMA4(s1,w13,a13) FMA4(s2,w14,a14) FMA4(s3,w15,a15)
    gh[j] = bj + ((s0+s1)+(s2+s3));
    __syncthreads();
    if (lane64) {
      float r  = sigmoidf_(g0 + gh[j]);
      float z  = sigmoidf_(g1 + gh[64+j]);
      float n  = tanhf(g2 + r*gh[128+j]);
      float hn = (1.0f - z)*n + z*h[j];
      h[j] = hn;
      hb[(size_t)t*64+j] = hn;
      g0 = n0; g1 = n1; g2 = n2;
    }
    __syncthreads();
  }
}

// ------------- post-MLP + all heads, one block per (b,t) -----------------
__global__ void __launch_bounds__(256) k_heads(
    const float* hs, const float* Wpost, const float* bpost,
    const float* Wharm, const float* bharm,
    const float* Wamp, const float* bamp,
    const float* Wnoise, const float* bnoise,
    const float* Wnamp, const float* bnamp,
    const float* WB, const float* bB,
    float* harm, float* nmag, float* fs) {
  int bt = blockIdx.x; int b = bt / Tn, t = bt % Tn;
  __shared__ float h64[64];
  __shared__ float fp[128];
  __shared__ float lg[256];
  __shared__ float red[8]; // mx0,mx1,sum0,sum1,amp0,amp1,namp0,namp1
  int tid = threadIdx.x;
  if (tid < 64) h64[tid] = hs[((size_t)b*Tn+t)*64+tid];
  __syncthreads();
  if (tid < 128) {
    float a = bpost[tid];
    #pragma unroll 8
    for (int i=0;i<64;i++) a += h64[i]*Wpost[i*128+tid];
    fp[tid] = fmaxf(a,0.0f);
  }
  __syncthreads();
  { // harmonic logits: tid -> (c = tid>>7, n = tid&127)
    int c = tid >> 7, n = tid & 127;
    float a = bharm[c*128+n];
    const float* w = Wharm + (size_t)c*128*128 + n;
    #pragma unroll 8
    for (int d=0;d<128;d++) a += fp[d]*w[d*128];
    lg[tid] = a;
  }
  __syncthreads();
  if (tid < 2) {
    const float* l = lg + tid*128;
    float mx = l[0];
    for (int n=1;n<128;n++) mx = fmaxf(mx,l[n]);
    float sm = 0.f; for (int n=0;n<128;n++) sm += expf(l[n]-mx);
    red[tid] = mx; red[2+tid] = sm;
    float aa = bamp[tid];
    for (int d=0;d<128;d++) aa += fp[d]*Wamp[tid*128+d];
    red[4+tid] = softplusf_(aa);
    float na = bnamp[tid];
    for (int d=0;d<128;d++) na += fp[d]*Wnamp[tid*128+d];
    red[6+tid] = softplusf_(na);
  } else if (tid == 2) {
    float bb = bB[0];
    for (int d=0;d<128;d++) bb += fp[d]*WB[d];
    atomicAdd(&fs[6+b], sigmoidf_(bb));
  }
  __syncthreads();
  { // harm_amps = softmax * amp
    int c = tid >> 7, n = tid & 127;
    float v = expf(lg[tid]-red[c]) / red[2+c] * red[4+c];
    harm[(((size_t)c*Bn + b)*Tn + t)*128 + n] = v;
  }
  // noise magnitudes: 2*513 outputs
  for (int o = tid; o < 2*NNn; o += 256) {
    int c = (o < NNn) ? 0 : 1; int n = o - c*NNn;
    float a = bnoise[c*NNn+n];
    const float* w = Wnoise + (size_t)c*128*NNn + n;
    #pragma unroll 8
    for (int d=0;d<128;d++) a += fp[d]*w[(size_t)d*NNn];
    nmag[(((size_t)c*Bn + b)*Tn + t)*NNn + n] = sigmoidf_(a) * red[6+c];
  }
}

// --------- inh + per-(b,k) frequency ratios r = k*sqrt(1+inh k^2) --------
__global__ void k_inh(float* fs, double* rk) {
  int tid = threadIdx.x; // 256
  __shared__ double inh_s[2];
  if (tid < 2) {
    float inh = fs[6+tid]*(1.0f/(float)Tn) * fs[2+tid];
    fs[8+tid] = inh;
    inh_s[tid] = (double)inh;
  }
  __syncthreads();
  int b = tid >> 7, k = (tid & 127) + 1;
  double kk = (double)k;
  rk[b*128 + (k-1)] = kk * sqrt(1.0 + inh_s[b]*kk*kk);
}

// ---------------- harmonic synthesis: thread per (b,s) -------------------
__global__ void __launch_bounds__(256) k_harm(
    const float* f0, const float* harm, const double* P,
    const double* rk, const float* fs, float* sigh) {
  int b = blockIdx.y;
  int s = blockIdx.x*256 + threadIdx.x; // < 96000 exactly
  __shared__ double rks[128];
  __shared__ float  rkf[128];
  if (threadIdx.x < 128) {
    double r = rk[b*128+threadIdx.x];
    rks[threadIdx.x] = r; rkf[threadIdx.x] = (float)r;
  }
  __syncthreads();
  const float* f = f0 + b*Tn;
  float posf = ((float)s + 0.5f) * (400.0f/96000.0f) - 0.5f;
  posf = fminf(fmaxf(posf, 0.0f), 399.0f);
  int lo = (int)floorf(posf);
  int hi = min(lo+1, 399);
  float fr = posf - (float)lo;
  float f0up = f[lo]*(1.0f-fr) + f[hi]*fr;
  double C;
  if (s < 120) {
    C = (double)(s+1) * (double)f[0];
  } else if (s < 95880) {
    int m = (s-120)/240;
    int j = s - 120 - 240*m;
    double fm = (double)f[m], fm1 = (double)f[m+1];
    double jp = (double)(j+1);
    C = 120.0*((double)f[0] + P[b*Tn+m]) + jp*fm + (fm1-fm)*jp*jp*(1.0/480.0);
  } else {
    C = 120.0*((double)f[0] + P[b*Tn+399]) + (double)(s-95880+1)*(double)f[399];
  }
  double Phi = C * (2.0*DPI/48000.0);
  const float* hLlo = harm + (((size_t)0*Bn + b)*Tn + lo)*128;
  const float* hLhi = harm + (((size_t)0*Bn + b)*Tn + hi)*128;
  const float* hRlo = harm + (((size_t)1*Bn + b)*Tn + lo)*128;
  const float* hRhi = harm + (((size_t)1*Bn + b)*Tn + hi)*128;
  float accL=0.f, accR=0.f;
  for (int k=0;k<128;k++) {
    float finst = f0up * rkf[k];
    if (finst < CUT) {
      double u = rks[k]*Phi * (1.0/(2.0*DPI));
      u -= floor(u);
      float sv = __sinf((float)u * 6.28318530717959f);
      float aL = hLlo[k]*(1.0f-fr) + hLhi[k]*fr;
      float aR = hRlo[k]*(1.0f-fr) + hRhi[k]*fr;
      accL += aL*sv; accR += aR*sv;
    }
  }
  float na = fs[4+b];
  sigh[((size_t)b*2+0)*Sn + s] = accL/na;
  sigh[((size_t)b*2+1)*Sn + s] = accR/na;
}

// ------ noise: frame -> window -> FFT -> shape -> iFFT -> window -> OLA ---
__global__ void __launch_bounds__(256) k_noise(
    const float* noiseL, const float* noiseR,
    const float* nmag, const float* fs, float* ola) {
  int t = blockIdx.x;       // 0..375
  int sig = blockIdx.y;     // b*2 + c
  int b = sig >> 1, c = sig & 1;
  const float* noise = (c==0 ? noiseL : noiseR) + (size_t)b*Sn;
  __shared__ float re[1024], im[1024];
  __shared__ float twc[512], tws[512];
  __shared__ float wdw[1024];
  int tid = threadIdx.x;
  for (int j=tid; j<512; j+=256) {
    float ang = (float)(2.0*DPI) * (float)j * (1.0f/1024.0f);
    twc[j] = cosf(ang); tws[j] = sinf(ang);
  }
  for (int i=tid; i<1024; i+=256)
    wdw[i] = 0.5f - 0.5f*cosf((float)(2.0*DPI)*(float)i*(1.0f/1024.0f));
  __syncthreads();
  for (int i=tid;i<1024;i+=256) {
    int q = t*HOPs + i - PADs;
    if (q < 0) q = -q;
    if (q >= Sn) q = 2*Sn - 2 - q;
    float v = noise[q]*wdw[i];
    int br = (int)(__brev((unsigned)i) >> 22);
    re[br] = v; im[br] = 0.0f;
  }
  __syncthreads();
  for (int st=1; st<=10; st++) {
    int half = 1<<(st-1);
    #pragma unroll
    for (int w=0;w<2;w++) {
      int bid = tid + w*256;
      int pos = bid & (half-1);
      int i0 = ((bid >> (st-1)) << st) + pos;
      int i1 = i0 + half;
      int j = pos << (10-st);
      float cr = twc[j], ci = -tws[j];
      float xr = re[i1], xi = im[i1];
      float tr = cr*xr - ci*xi, ti = cr*xi + ci*xr;
      float ar = re[i0], ai = im[i0];
      re[i1] = ar - tr; im[i1] = ai - ti;
      re[i0] = ar + tr; im[i0] = ai + ti;
    }
    __syncthreads();
  }
  float f0m = fs[b];
  float pp = ((float)t + 0.5f) * (400.0f/376.0f) - 0.5f;
  pp = fminf(fmaxf(pp,0.0f),399.0f);
  int tlo = (int)floorf(pp); int thi = min(tlo+1, 399); float tfr = pp - (float)tlo;
  const float* nm = nmag + (((size_t)c*Bn + b)*Tn)*NNn;
  for (int k=tid;k<=512;k+=256) {
    float src = (float)k * 46.875f / f0m * (513.0f/128.0f);
    src = fminf(fmaxf(src,0.0f),512.0f);
    int flo = (int)src; int fhi = min(flo+1,512); float ffr = src - (float)flo;
    float vlo = nm[(size_t)tlo*NNn+flo]*(1.0f-tfr) + nm[(size_t)thi*NNn+flo]*tfr;
    float vhi = nm[(size_t)tlo*NNn+fhi]*(1.0f-tfr) + nm[(size_t)thi*NNn+fhi]*tfr;
    float mag = vlo + ffr*(vhi-vlo);
    re[k] *= mag; im[k] *= mag;
  }
  __syncthreads();
  for (int k=tid+513; k<1024; k+=256) {
    re[k] = re[1024-k]; im[k] = -im[1024-k];
  }
  __syncthreads();
  for (int i=tid;i<1024;i+=256) {
    int j = (int)(__brev((unsigned)i)>>22);
    if (i < j) {
      float a=re[i]; re[i]=re[j]; re[j]=a;
      float bb=im[i]; im[i]=im[j]; im[j]=bb;
    }
  }
  __syncthreads();
  for (int st=1; st<=10; st++) {
    int half = 1<<(st-1);
    #pragma unroll
    for (int w=0;w<2;w++) {
      int bid = tid + w*256;
      int pos = bid & (half-1);
      int i0 = ((bid >> (st-1)) << st) + pos;
      int i1 = i0 + half;
      int j = pos << (10-st);
      float cr = twc[j], ci = tws[j];
      float xr = re[i1], xi = im[i1];
      float tr = cr*xr - ci*xi, ti = cr*xi + ci*xr;
      float ar = re[i0], ai = im[i0];
      re[i1] = ar - tr; im[i1] = ai - ti;
      re[i0] = ar + tr; im[i0] = ai + ti;
    }
    __syncthreads();
  }
  float* olab = ola + (size_t)sig*LPn;
  for (int i=tid;i<1024;i+=256) {
    float y = re[i] * (1.0f/1024.0f) * wdw[i];
    atomicAdd(&olab[t*HOPs + i], y);
  }
}

// ------------- final: (harm + ola/wsq) * loudness ------------------------
__global__ void __launch_bounds__(256) k_final(
    const float* loud, const float* sigh, const float* ola, float* out) {
  int b = blockIdx.y;
  int s = blockIdx.x*256 + threadIdx.x;
  float posf = ((float)s + 0.5f)*(400.0f/96000.0f) - 0.5f;
  posf = fminf(fmaxf(posf,0.0f),399.0f);
  int lo=(int)floorf(posf); int hi=min(lo+1,399); float fr=posf-(float)lo;
  const float* ld = loud + b*Tn;
  float lv = exp10f(ld[lo]*0.05f)*(1.0f-fr) + exp10f(ld[hi]*0.05f)*fr;
  int p = PADs + s;
  int t0 = (p >= 1023) ? ((p - 1023 + 255) >> 8) : 0;
  int t1 = min(TS-1, p >> 8);
  float wsq = 0.0f;
  for (int t=t0;t<=t1;t++) {
    int i = p - (t<<8);
    float w = 0.5f - 0.5f*cosf((float)(2.0*DPI)*(float)i*(1.0f/1024.0f));
    wsq += w*w;
  }
  float denom = (wsq > 1e-11f) ? wsq : 1.0f;
  for (int c=0;c<2;c++) {
    float hv = sigh[((size_t)b*2+c)*Sn+s];
    float nv = ola[(size_t)(b*2+c)*LPn + p] / denom;
    out[((size_t)b*2+c)*Sn + s] = (hv + nv)*lv;
  }
}

extern "C" void kernel_launch(void* const* d_in, const int* in_sizes, int n_in,
                              void* d_out, int out_size, void* d_ws, size_t ws_size,
                              hipStream_t stream) {
  const float* f0    = (const float*)d_in[0];
  const float* loud  = (const float*)d_in[1];
  const float* nL    = (const float*)d_in[2];
  const float* nR    = (const float*)d_in[3];
  const float* Wp1   = (const float*)d_in[4];  const float* bp1 = (const float*)d_in[5];
  const float* Wp2   = (const float*)d_in[6];  const float* bp2 = (const float*)d_in[7];
  const float* Wih   = (const float*)d_in[8];  const float* Whh = (const float*)d_in[9];
  const float* bih   = (const float*)d_in[10]; const float* bhh = (const float*)d_in[11];
  const float* Wpost = (const float*)d_in[12]; const float* bpost=(const float*)d_in[13];
  const float* Wharm = (const float*)d_in[14]; const float* bharm=(const float*)d_in[15];
  const float* Wamp  = (const float*)d_in[16]; const float* bamp =(const float*)d_in[17];
  const float* Wnoise= (const float*)d_in[18]; const float* bnoise=(const float*)d_in[19];
  const float* Wnamp = (const float*)d_in[20]; const float* bnamp=(const float*)d_in[21];
  const float* WB    = (const float*)d_in[22]; const float* bB  = (const float*)d_in[23];
  const int*   vel   = (const int*)d_in[24];
  float* out = (float*)d_out;

  char* w = (char*)d_ws;
  double* P    = (double*)w; w += (size_t)Bn*Tn*sizeof(double);
  double* rk   = (double*)w; w += (size_t)Bn*128*sizeof(double);
  float* gi    = (float*)w;  w += (size_t)Bn*Tn*192*sizeof(float);
  float* hsb   = (float*)w;  w += (size_t)Bn*Tn*64*sizeof(float);
  float* harm  = (float*)w;  w += (size_t)2*Bn*Tn*128*sizeof(float);
  float* nmag  = (float*)w;  w += (size_t)2*Bn*Tn*NNn*sizeof(float);
  float* sigh  = (float*)w;  w += (size_t)Bn*2*Sn*sizeof(float);
  float* ola   = (float*)w;  w += (size_t)Bn*2*LPn*sizeof(float);
  float* fscal = (float*)w;  w += 32*sizeof(float);

  hipMemsetAsync(ola, 0, (size_t)Bn*2*LPn*sizeof(float), stream);
  hipMemsetAsync(fscal, 0, 32*sizeof(float), stream);

  k_setup<<<1, 64, 0, stream>>>(f0, fscal, P);
  k_frame1<<<Bn*Tn, 128, 0, stream>>>(f0, vel, Wp1,bp1, Wp2,bp2, Wih,bih, gi);
  k_gru<<<Bn, 192, 0, stream>>>(gi, Whh, bhh, hsb);
  k_heads<<<Bn*Tn, 256, 0, stream>>>(hsb, Wpost,bpost, Wharm,bharm, Wamp,bamp,
                                     Wnoise,bnoise, Wnamp,bnamp, WB,bB,
                                     harm, nmag, fscal);
  k_inh<<<1, 256, 0, stream>>>(fscal, rk);
  dim3 gh(Sn/256, Bn);
  k_harm<<<gh, 256, 0, stream>>>(f0, harm, P, rk, fscal, sigh);
  dim3 gn(TS, Bn*2);
  k_noise<<<gn, 256, 0, stream>>>(nL, nR, nmag, fscal, ola);
  dim3 gf(Sn/256, Bn);
  k_final<<<gf, 256, 0, stream>>>(loud, sigh, ola, out);
}

// Round 3
// 504.938 us; speedup vs baseline: 1.2667x; 1.0123x over previous
//
#include <hip/hip_runtime.h>
#include <math.h>

#define Tn   400
#define Bn   2
#define Sn   96000
#define NHh  128
#define NNn  513
#define NFFT 1024
#define HOPs 256
#define PADs 512
#define TS   376      // 1 + Sn/HOPs
#define LPn  97024    // NFFT + (TS-1)*HOPs
#define CUT  21600.0f // SR*0.45
#define DPI  3.14159265358979323846

__device__ __forceinline__ float sigmoidf_(float x){ return 1.0f/(1.0f+expf(-x)); }
__device__ __forceinline__ float softplusf_(float x){ return fmaxf(x,0.0f)+log1pf(expf(-fabsf(x))); }

// ---------------- setup: per-batch scalars + f64 prefix table -------------
__global__ void k_setup(const float* f0, float* fs, double* P) {
  int b = threadIdx.x;
  if (b < Bn) {
    const float* f = f0 + b*Tn;
    double sm = 0.0;
    for (int t=0;t<Tn;t++) sm += fmax((double)f[t], 20.0);
    float f0m = (float)(sm / (double)Tn);
    fs[b] = f0m;
    float midi = 69.0f + 12.0f * log2f(f0m/440.0f);
    fs[2+b] = 0.0008f * expf(-(midi-21.0f)*(1.0f/88.0f) * 2.302585093f); // b_max
    double* Pb = P + b*Tn;
    double acc = 0.0;
    for (int m=0;m<Tn;m++){ Pb[m] = acc; if (m < Tn-1) acc += (double)f[m] + (double)f[m+1]; }
    double Ctot = 120.0*((double)f[0] + Pb[Tn-1] + (double)f[Tn-1]);
    double fupmean = Ctot / (double)Sn;
    int cnt = 0;
    for (int k=1;k<=NHh;k++) if ((float)k * (float)fupmean < CUT) cnt++;
    if (cnt < 1) cnt = 1;
    fs[4+b] = (float)cnt;
  }
}

// -------- frame-rate: encode + pre MLP + gi = x@W_ih^T + b_ih -------------
__global__ void __launch_bounds__(128) k_frame1(
    const float* f0, const int* vel,
    const float* Wp1, const float* bp1,
    const float* Wp2, const float* bp2,
    const float* Wih, const float* bih,
    float* gi) {
  int bt = blockIdx.x; int b = bt / Tn, t = bt % Tn;
  __shared__ float x[72];
  __shared__ float y1[128];
  __shared__ float y2[128];
  int tid = threadIdx.x;
  if (tid < 72) {
    if (tid < 64) {
      float fv = f0[b*Tn+t];
      float fsv = fmaxf(fv, 20.0f);
      float fn = (logf(fsv) - 2.99573227355399f) * (1.0f/5.52146091786225f);
      fn = fminf(fmaxf(fn,0.0f),1.0f);
      int j = (tid>>1) + 1;
      float ang = (float)DPI * (float)j * fn;
      x[tid] = (tid & 1) ? cosf(ang) : sinf(ang);
    } else {
      int i = tid - 64;
      float vn = fminf(fmaxf((float)vel[b]*(1.0f/7.0f),0.0f),1.0f);
      int j = (i>>1)+1;
      float ang = (float)DPI * (float)j * vn;
      x[tid] = (i & 1) ? cosf(ang) : sinf(ang);
    }
  }
  __syncthreads();
  {
    float a = bp1[tid];
    #pragma unroll 8
    for (int i=0;i<72;i++) a += x[i]*Wp1[i*128+tid];
    y1[tid] = fmaxf(a,0.0f);
  }
  __syncthreads();
  {
    float a = bp2[tid];
    #pragma unroll 8
    for (int i=0;i<128;i++) a += y1[i]*Wp2[i*128+tid];
    y2[tid] = fmaxf(a,0.0f);
  }
  __syncthreads();
  float* gout = gi + ((size_t)b*Tn + t)*192;
  for (int g = tid; g < 192; g += 128) {
    float s = bih[g];
    const float* wr = Wih + g*128;
    #pragma unroll 8
    for (int d=0; d<128; d++) s += y2[d]*wr[d];
    gout[g] = s;
  }
}

// ---------------- GRU: single wave per batch, wave-synchronous ------------
// R1 lesson: per-step __syncthreads forces s_waitcnt vmcnt(0) before
// s_barrier, draining the h-store AND the gi prefetch every step (~1000
// extra cycles on the 400-long serial chain). This version uses ONE wave:
// thread j owns h_j + W_hh rows {j, 64+j, 128+j} in registers; h_i is
// broadcast via v_readlane (constant lane). No LDS, no barriers at all.
#define RL(x, l) __int_as_float(__builtin_amdgcn_readlane(__float_as_int(x), (l)))

__global__ void __launch_bounds__(64, 1) k_gru(const float* __restrict__ gi,
                                               const float* __restrict__ Whh,
                                               const float* __restrict__ bhh,
                                               float* __restrict__ hsout) {
  int b = blockIdx.x;
  int j = threadIdx.x; // 0..63
  float4 wr[16], wz[16], wn[16];
  {
    const float4* Wr = (const float4*)(Whh + (size_t)j*64);
    const float4* Wz = (const float4*)(Whh + (size_t)(64+j)*64);
    const float4* Wn = (const float4*)(Whh + (size_t)(128+j)*64);
    #pragma unroll
    for (int i=0;i<16;i++){ wr[i]=Wr[i]; wz[i]=Wz[i]; wn[i]=Wn[i]; }
  }
  float br = bhh[j], bz = bhh[64+j], bn = bhh[128+j];
  const float* gib = gi + (size_t)b*Tn*192;
  float* hb = hsout + (size_t)b*Tn*64;
  float h = 0.0f;
  float g0 = gib[j], g1 = gib[64+j], g2 = gib[128+j];
  for (int t=0;t<Tn;t++) {
    // prefetch next step's gi (no barrier anywhere -> truly overlaps)
    const float* gnx = gib + (size_t)((t+1 < Tn) ? t+1 : t)*192;
    float n0 = gnx[j], n1 = gnx[64+j], n2 = gnx[128+j];
    float ar0=0.f,ar1=0.f,ar2=0.f,ar3=0.f;
    float az0=0.f,az1=0.f,az2=0.f,az3=0.f;
    float an0=0.f,an1=0.f,an2=0.f,an3=0.f;
    #pragma unroll
    for (int i=0;i<16;i++) {
      float h0 = RL(h, 4*i+0);
      float h1 = RL(h, 4*i+1);
      float h2 = RL(h, 4*i+2);
      float h3 = RL(h, 4*i+3);
      ar0 = fmaf(wr[i].x, h0, ar0); az0 = fmaf(wz[i].x, h0, az0); an0 = fmaf(wn[i].x, h0, an0);
      ar1 = fmaf(wr[i].y, h1, ar1); az1 = fmaf(wz[i].y, h1, az1); an1 = fmaf(wn[i].y, h1, an1);
      ar2 = fmaf(wr[i].z, h2, ar2); az2 = fmaf(wz[i].z, h2, az2); an2 = fmaf(wn[i].z, h2, an2);
      ar3 = fmaf(wr[i].w, h3, ar3); az3 = fmaf(wz[i].w, h3, az3); an3 = fmaf(wn[i].w, h3, an3);
    }
    float ghr = br + ((ar0+ar1)+(ar2+ar3));
    float ghz = bz + ((az0+az1)+(az2+az3));
    float ghn = bn + ((an0+an1)+(an2+an3));
    float r  = sigmoidf_(g0 + ghr);
    float z  = sigmoidf_(g1 + ghz);
    float n  = tanhf(g2 + r*ghn);
    h = (1.0f - z)*n + z*h;
    hb[(size_t)t*64+j] = h;
    g0 = n0; g1 = n1; g2 = n2;
  }
}

// ------------- post-MLP + all heads, one block per (b,t) -----------------
__global__ void __launch_bounds__(256) k_heads(
    const float* hs, const float* Wpost, const float* bpost,
    const float* Wharm, const float* bharm,
    const float* Wamp, const float* bamp,
    const float* Wnoise, const float* bnoise,
    const float* Wnamp, const float* bnamp,
    const float* WB, const float* bB,
    float* harm, float* nmag, float* fs) {
  int bt = blockIdx.x; int b = bt / Tn, t = bt % Tn;
  __shared__ float h64[64];
  __shared__ float fp[128];
  __shared__ float lg[256];
  __shared__ float red[8]; // mx0,mx1,sum0,sum1,amp0,amp1,namp0,namp1
  int tid = threadIdx.x;
  if (tid < 64) h64[tid] = hs[((size_t)b*Tn+t)*64+tid];
  __syncthreads();
  if (tid < 128) {
    float a = bpost[tid];
    #pragma unroll 8
    for (int i=0;i<64;i++) a += h64[i]*Wpost[i*128+tid];
    fp[tid] = fmaxf(a,0.0f);
  }
  __syncthreads();
  { // harmonic logits: tid -> (c = tid>>7, n = tid&127)
    int c = tid >> 7, n = tid & 127;
    float a = bharm[c*128+n];
    const float* w = Wharm + (size_t)c*128*128 + n;
    #pragma unroll 8
    for (int d=0;d<128;d++) a += fp[d]*w[d*128];
    lg[tid] = a;
  }
  __syncthreads();
  if (tid < 2) {
    const float* l = lg + tid*128;
    float mx = l[0];
    for (int n=1;n<128;n++) mx = fmaxf(mx,l[n]);
    float sm = 0.f; for (int n=0;n<128;n++) sm += expf(l[n]-mx);
    red[tid] = mx; red[2+tid] = sm;
    float aa = bamp[tid];
    for (int d=0;d<128;d++) aa += fp[d]*Wamp[tid*128+d];
    red[4+tid] = softplusf_(aa);
    float na = bnamp[tid];
    for (int d=0;d<128;d++) na += fp[d]*Wnamp[tid*128+d];
    red[6+tid] = softplusf_(na);
  } else if (tid == 2) {
    float bb = bB[0];
    for (int d=0;d<128;d++) bb += fp[d]*WB[d];
    atomicAdd(&fs[6+b], sigmoidf_(bb));
  }
  __syncthreads();
  { // harm_amps = softmax * amp
    int c = tid >> 7, n = tid & 127;
    float v = expf(lg[tid]-red[c]) / red[2+c] * red[4+c];
    harm[(((size_t)c*Bn + b)*Tn + t)*128 + n] = v;
  }
  // noise magnitudes: 2*513 outputs
  for (int o = tid; o < 2*NNn; o += 256) {
    int c = (o < NNn) ? 0 : 1; int n = o - c*NNn;
    float a = bnoise[c*NNn+n];
    const float* w = Wnoise + (size_t)c*128*NNn + n;
    #pragma unroll 8
    for (int d=0;d<128;d++) a += fp[d]*w[(size_t)d*NNn];
    nmag[(((size_t)c*Bn + b)*Tn + t)*NNn + n] = sigmoidf_(a) * red[6+c];
  }
}

// --------- inh + per-(b,k) frequency ratios r = k*sqrt(1+inh k^2) --------
__global__ void k_inh(float* fs, double* rk) {
  int tid = threadIdx.x; // 256
  __shared__ double inh_s[2];
  if (tid < 2) {
    float inh = fs[6+tid]*(1.0f/(float)Tn) * fs[2+tid];
    fs[8+tid] = inh;
    inh_s[tid] = (double)inh;
  }
  __syncthreads();
  int b = tid >> 7, k = (tid & 127) + 1;
  double kk = (double)k;
  rk[b*128 + (k-1)] = kk * sqrt(1.0 + inh_s[b]*kk*kk);
}

// ---------------- harmonic synthesis: thread per (b,s) -------------------
__global__ void __launch_bounds__(256) k_harm(
    const float* f0, const float* harm, const double* P,
    const double* rk, const float* fs, float* sigh) {
  int b = blockIdx.y;
  int s = blockIdx.x*256 + threadIdx.x; // < 96000 exactly
  __shared__ double rks[128];
  __shared__ float  rkf[128];
  if (threadIdx.x < 128) {
    double r = rk[b*128+threadIdx.x];
    rks[threadIdx.x] = r; rkf[threadIdx.x] = (float)r;
  }
  __syncthreads();
  const float* f = f0 + b*Tn;
  float posf = ((float)s + 0.5f) * (400.0f/96000.0f) - 0.5f;
  posf = fminf(fmaxf(posf, 0.0f), 399.0f);
  int lo = (int)floorf(posf);
  int hi = min(lo+1, 399);
  float fr = posf - (float)lo;
  float f0up = f[lo]*(1.0f-fr) + f[hi]*fr;
  double C;
  if (s < 120) {
    C = (double)(s+1) * (double)f[0];
  } else if (s < 95880) {
    int m = (s-120)/240;
    int j = s - 120 - 240*m;
    double fm = (double)f[m], fm1 = (double)f[m+1];
    double jp = (double)(j+1);
    C = 120.0*((double)f[0] + P[b*Tn+m]) + jp*fm + (fm1-fm)*jp*jp*(1.0/480.0);
  } else {
    C = 120.0*((double)f[0] + P[b*Tn+399]) + (double)(s-95880+1)*(double)f[399];
  }
  double Phi = C * (2.0*DPI/48000.0);
  const float* hLlo = harm + (((size_t)0*Bn + b)*Tn + lo)*128;
  const float* hLhi = harm + (((size_t)0*Bn + b)*Tn + hi)*128;
  const float* hRlo = harm + (((size_t)1*Bn + b)*Tn + lo)*128;
  const float* hRhi = harm + (((size_t)1*Bn + b)*Tn + hi)*128;
  float accL=0.f, accR=0.f;
  for (int k=0;k<128;k++) {
    float finst = f0up * rkf[k];
    if (finst < CUT) {
      double u = rks[k]*Phi * (1.0/(2.0*DPI));
      u -= floor(u);
      float sv = __sinf((float)u * 6.28318530717959f);
      float aL = hLlo[k]*(1.0f-fr) + hLhi[k]*fr;
      float aR = hRlo[k]*(1.0f-fr) + hRhi[k]*fr;
      accL += aL*sv; accR += aR*sv;
    }
  }
  float na = fs[4+b];
  sigh[((size_t)b*2+0)*Sn + s] = accL/na;
  sigh[((size_t)b*2+1)*Sn + s] = accR/na;
}

// ------ noise: frame -> window -> FFT -> shape -> iFFT -> window -> OLA ---
__global__ void __launch_bounds__(256) k_noise(
    const float* noiseL, const float* noiseR,
    const float* nmag, const float* fs, float* ola) {
  int t = blockIdx.x;       // 0..375
  int sig = blockIdx.y;     // b*2 + c
  int b = sig >> 1, c = sig & 1;
  const float* noise = (c==0 ? noiseL : noiseR) + (size_t)b*Sn;
  __shared__ float re[1024], im[1024];
  __shared__ float twc[512], tws[512];
  __shared__ float wdw[1024];
  int tid = threadIdx.x;
  for (int j=tid; j<512; j+=256) {
    float ang = (float)(2.0*DPI) * (float)j * (1.0f/1024.0f);
    twc[j] = cosf(ang); tws[j] = sinf(ang);
  }
  for (int i=tid; i<1024; i+=256)
    wdw[i] = 0.5f - 0.5f*cosf((float)(2.0*DPI)*(float)i*(1.0f/1024.0f));
  __syncthreads();
  for (int i=tid;i<1024;i+=256) {
    int q = t*HOPs + i - PADs;
    if (q < 0) q = -q;
    if (q >= Sn) q = 2*Sn - 2 - q;
    float v = noise[q]*wdw[i];
    int br = (int)(__brev((unsigned)i) >> 22);
    re[br] = v; im[br] = 0.0f;
  }
  __syncthreads();
  for (int st=1; st<=10; st++) {
    int half = 1<<(st-1);
    #pragma unroll
    for (int w=0;w<2;w++) {
      int bid = tid + w*256;
      int pos = bid & (half-1);
      int i0 = ((bid >> (st-1)) << st) + pos;
      int i1 = i0 + half;
      int j = pos << (10-st);
      float cr = twc[j], ci = -tws[j];
      float xr = re[i1], xi = im[i1];
      float tr = cr*xr - ci*xi, ti = cr*xi + ci*xr;
      float ar = re[i0], ai = im[i0];
      re[i1] = ar - tr; im[i1] = ai - ti;
      re[i0] = ar + tr; im[i0] = ai + ti;
    }
    __syncthreads();
  }
  float f0m = fs[b];
  float pp = ((float)t + 0.5f) * (400.0f/376.0f) - 0.5f;
  pp = fminf(fmaxf(pp,0.0f),399.0f);
  int tlo = (int)floorf(pp); int thi = min(tlo+1, 399); float tfr = pp - (float)tlo;
  const float* nm = nmag + (((size_t)c*Bn + b)*Tn)*NNn;
  for (int k=tid;k<=512;k+=256) {
    float src = (float)k * 46.875f / f0m * (513.0f/128.0f);
    src = fminf(fmaxf(src,0.0f),512.0f);
    int flo = (int)src; int fhi = min(flo+1,512); float ffr = src - (float)flo;
    float vlo = nm[(size_t)tlo*NNn+flo]*(1.0f-tfr) + nm[(size_t)thi*NNn+flo]*tfr;
    float vhi = nm[(size_t)tlo*NNn+fhi]*(1.0f-tfr) + nm[(size_t)thi*NNn+fhi]*tfr;
    float mag = vlo + ffr*(vhi-vlo);
    re[k] *= mag; im[k] *= mag;
  }
  __syncthreads();
  for (int k=tid+513; k<1024; k+=256) {
    re[k] = re[1024-k]; im[k] = -im[1024-k];
  }
  __syncthreads();
  for (int i=tid;i<1024;i+=256) {
    int j = (int)(__brev((unsigned)i)>>22);
    if (i < j) {
      float a=re[i]; re[i]=re[j]; re[j]=a;
      float bb=im[i]; im[i]=im[j]; im[j]=bb;
    }
  }
  __syncthreads();
  for (int st=1; st<=10; st++) {
    int half = 1<<(st-1);
    #pragma unroll
    for (int w=0;w<2;w++) {
      int bid = tid + w*256;
      int pos = bid & (half-1);
      int i0 = ((bid >> (st-1)) << st) + pos;
      int i1 = i0 + half;
      int j = pos << (10-st);
      float cr = twc[j], ci = tws[j];
      float xr = re[i1], xi = im[i1];
      float tr = cr*xr - ci*xi, ti = cr*xi + ci*xr;
      float ar = re[i0], ai = im[i0];
      re[i1] = ar - tr; im[i1] = ai - ti;
      re[i0] = ar + tr; im[i0] = ai + ti;
    }
    __syncthreads();
  }
  float* olab = ola + (size_t)sig*LPn;
  for (int i=tid;i<1024;i+=256) {
    float y = re[i] * (1.0f/1024.0f) * wdw[i];
    atomicAdd(&olab[t*HOPs + i], y);
  }
}

// ------------- final: (harm + ola/wsq) * loudness ------------------------
__global__ void __launch_bounds__(256) k_final(
    const float* loud, const float* sigh, const float* ola, float* out) {
  int b = blockIdx.y;
  int s = blockIdx.x*256 + threadIdx.x;
  float posf = ((float)s + 0.5f)*(400.0f/96000.0f) - 0.5f;
  posf = fminf(fmaxf(posf,0.0f),399.0f);
  int lo=(int)floorf(posf); int hi=min(lo+1,399); float fr=posf-(float)lo;
  const float* ld = loud + b*Tn;
  float lv = exp10f(ld[lo]*0.05f)*(1.0f-fr) + exp10f(ld[hi]*0.05f)*fr;
  int p = PADs + s;
  int t0 = (p >= 1023) ? ((p - 1023 + 255) >> 8) : 0;
  int t1 = min(TS-1, p >> 8);
  float wsq = 0.0f;
  for (int t=t0;t<=t1;t++) {
    int i = p - (t<<8);
    float w = 0.5f - 0.5f*cosf((float)(2.0*DPI)*(float)i*(1.0f/1024.0f));
    wsq += w*w;
  }
  float denom = (wsq > 1e-11f) ? wsq : 1.0f;
  for (int c=0;c<2;c++) {
    float hv = sigh[((size_t)b*2+c)*Sn+s];
    float nv = ola[(size_t)(b*2+c)*LPn + p] / denom;
    out[((size_t)b*2+c)*Sn + s] = (hv + nv)*lv;
  }
}

extern "C" void kernel_launch(void* const* d_in, const int* in_sizes, int n_in,
                              void* d_out, int out_size, void* d_ws, size_t ws_size,
                              hipStream_t stream) {
  const float* f0    = (const float*)d_in[0];
  const float* loud  = (const float*)d_in[1];
  const float* nL    = (const float*)d_in[2];
  const float* nR    = (const float*)d_in[3];
  const float* Wp1   = (const float*)d_in[4];  const float* bp1 = (const float*)d_in[5];
  const float* Wp2   = (const float*)d_in[6];  const float* bp2 = (const float*)d_in[7];
  const float* Wih   = (const float*)d_in[8];  const float* Whh = (const float*)d_in[9];
  const float* bih   = (const float*)d_in[10]; const float* bhh = (const float*)d_in[11];
  const float* Wpost = (const float*)d_in[12]; const float* bpost=(const float*)d_in[13];
  const float* Wharm = (const float*)d_in[14]; const float* bharm=(const float*)d_in[15];
  const float* Wamp  = (const float*)d_in[16]; const float* bamp =(const float*)d_in[17];
  const float* Wnoise= (const float*)d_in[18]; const float* bnoise=(const float*)d_in[19];
  const float* Wnamp = (const float*)d_in[20]; const float* bnamp=(const float*)d_in[21];
  const float* WB    = (const float*)d_in[22]; const float* bB  = (const float*)d_in[23];
  const int*   vel   = (const int*)d_in[24];
  float* out = (float*)d_out;

  char* w = (char*)d_ws;
  double* P    = (double*)w; w += (size_t)Bn*Tn*sizeof(double);
  double* rk   = (double*)w; w += (size_t)Bn*128*sizeof(double);
  float* gi    = (float*)w;  w += (size_t)Bn*Tn*192*sizeof(float);
  float* hsb   = (float*)w;  w += (size_t)Bn*Tn*64*sizeof(float);
  float* harm  = (float*)w;  w += (size_t)2*Bn*Tn*128*sizeof(float);
  float* nmag  = (float*)w;  w += (size_t)2*Bn*Tn*NNn*sizeof(float);
  float* sigh  = (float*)w;  w += (size_t)Bn*2*Sn*sizeof(float);
  float* ola   = (float*)w;  w += (size_t)Bn*2*LPn*sizeof(float);
  float* fscal = (float*)w;  w += 32*sizeof(float);

  hipMemsetAsync(ola, 0, (size_t)Bn*2*LPn*sizeof(float), stream);
  hipMemsetAsync(fscal, 0, 32*sizeof(float), stream);

  k_setup<<<1, 64, 0, stream>>>(f0, fscal, P);
  k_frame1<<<Bn*Tn, 128, 0, stream>>>(f0, vel, Wp1,bp1, Wp2,bp2, Wih,bih, gi);
  k_gru<<<Bn, 64, 0, stream>>>(gi, Whh, bhh, hsb);
  k_heads<<<Bn*Tn, 256, 0, stream>>>(hsb, Wpost,bpost, Wharm,bharm, Wamp,bamp,
                                     Wnoise,bnoise, Wnamp,bnamp, WB,bB,
                                     harm, nmag, fscal);
  k_inh<<<1, 256, 0, stream>>>(fscal, rk);
  dim3 gh(Sn/256, Bn);
  k_harm<<<gh, 256, 0, stream>>>(f0, harm, P, rk, fscal, sigh);
  dim3 gn(TS, Bn*2);
  k_noise<<<gn, 256, 0, stream>>>(nL, nR, nmag, fscal, ola);
  dim3 gf(Sn/256, Bn);
  k_final<<<gf, 256, 0, stream>>>(loud, sigh, ola, out);
}